// Round 8
// baseline (178.856 us; speedup 1.0000x reference)
//
#include <hip/hip_runtime.h>
#include <hip/hip_bf16.h>

typedef short short8 __attribute__((ext_vector_type(8)));
typedef float float4v __attribute__((ext_vector_type(4)));

#define NIMG 32
#define CIN 256
#define COUT 256
#define HH 56
#define WW 56
#define HP 58
#define WP 58
#define PIXIMG (HH * WW)          /* 3136 */
#define TOTPIX (NIMG * PIXIMG)    /* 100352 */
#define OUTSTRIDE_N (COUT * PIXIMG)

static constexpr size_t XT_ELEMS = (size_t)NIMG * HP * WP * CIN; // bf16
static constexpr size_t WT_ELEMS = (size_t)9 * COUT * CIN;       // bf16

// fp32 -> bf16 bits, round-to-nearest-even (finite inputs only)
static __device__ __forceinline__ unsigned short f2bf(float f) {
    unsigned int u = __builtin_bit_cast(unsigned int, f);
    u = (u + 0x7fffu + ((u >> 16) & 1u)) >> 16;
    return (unsigned short)u;
}

// async global(16B/lane) -> LDS (wave-uniform base + lane*16)
static __device__ __forceinline__ void gl16(const unsigned short* g, char* l) {
    __builtin_amdgcn_global_load_lds(
        (const __attribute__((address_space(1))) void*)g,
        (__attribute__((address_space(3))) void*)l, 16, 0, 0);
}

// ---------------------------------------------------------------------------
// x (NCHW fp32) -> x_t[n][h'][w'][ic] bf16, padded; halo zeroed in-kernel.
// ---------------------------------------------------------------------------
__global__ __launch_bounds__(256) void k_transpose(const float* __restrict__ x,
                                                   unsigned short* __restrict__ xt) {
    int b   = blockIdx.x;
    int icb = b & 3;
    int hp  = (b >> 2) % HP;    // padded output row 0..57
    int n   = b / (4 * HP);
    unsigned short* rowb = xt + ((size_t)(n * HP + hp) * WP) * CIN + icb * 64;
    int t = threadIdx.x;

    if (hp == 0 || hp == HP - 1) {
        for (int idx = t; idx < WP * 8; idx += 256) {
            int wq = idx >> 3, q = idx & 7;
            *(uint4*)(rowb + (size_t)wq * CIN + q * 8) = (uint4){0, 0, 0, 0};
        }
        return;
    }
    int h = hp - 1;
    __shared__ __align__(16) char lds[64 * 128]; // [w 64][ic 64] bf16, swizzled
    int w = t & 63, icl0 = t >> 6;
    if (w < WW) {
        const float* src = x + ((size_t)(n * CIN + icb * 64 + icl0) * HH + h) * WW + w;
#pragma unroll
        for (int j = 0; j < 16; ++j) {
            float v = src[(size_t)(j * 4) * PIXIMG];
            int icl = icl0 + j * 4;
            *(unsigned short*)(lds + w * 128 + ((icl * 2) ^ ((w & 7) << 4))) = f2bf(v);
        }
    }
    __syncthreads();
    int ic4 = t & 15, wr = t >> 4;
    unsigned short* dst = rowb + (size_t)CIN + ic4 * 4; // w'=1 base
#pragma unroll
    for (int p = 0; p < 4; ++p) {
        int w2 = wr + p * 16;
        if (w2 < WW) {
            uint2 v = *(const uint2*)(lds + w2 * 128 + ((ic4 * 8) ^ ((w2 & 7) << 4)));
            *(uint2*)(dst + (size_t)w2 * CIN) = v;
        }
    }
    if (t < 32) { // zero w'=0 and w'=57 columns
        int col = (t >> 4) * (WP - 1);
        *(uint2*)(rowb + (size_t)col * CIN + (t & 15) * 4) = (uint2){0, 0};
    }
}

// ---------------------------------------------------------------------------
// wt[tap][oc][ic] = bf16(weight * mask)
// ---------------------------------------------------------------------------
__global__ __launch_bounds__(256) void k_prepw(const float* __restrict__ wgt,
                                               const float* __restrict__ msk,
                                               unsigned short* __restrict__ wt) {
    int t = blockIdx.x * 256 + threadIdx.x; // t = oc*256 + ic
    const float* wp = wgt + (size_t)t * 9;
    const float* mp = msk + (size_t)t * 9;
#pragma unroll
    for (int tap = 0; tap < 9; ++tap)
        wt[(size_t)tap * (COUT * CIN) + t] = f2bf(wp[tap] * mp[tap]);
}

// ---------------------------------------------------------------------------
// Main conv: 9 shifted GEMMs, 128x128 tile, 4 waves (2x2), BK=32,
// TRUE double-buffer in 32KB LDS with counted vmcnt (T3 minimum 2-phase).
// Round-8 fix vs r7: barriers are `s_waitcnt lgkmcnt(0); s_barrier` — the
// raw s_barrier let waves cross with ds_reads still in the LDS pipe (hipcc
// sinks register-only MFMAs + their lgkmcnt guards past inline-asm barriers,
// rule #18 class), so the immediate post-barrier STAGE overwrite of the
// just-read buffer raced the in-flight reads (r7 absmax 0.25). lgkmcnt(0)
// before s_barrier pins the ds_reads (memory ops can't cross the clobber);
// counted vmcnt(4) global pipeline is preserved — never vmcnt(0) in loop.
// ---------------------------------------------------------------------------
__global__ __launch_bounds__(256, 4) void k_conv(const unsigned short* __restrict__ xt,
                                                 const unsigned short* __restrict__ wt,
                                                 float* __restrict__ out) {
    __shared__ __align__(16) char lds[32768];

    const int t    = threadIdx.x;
    const int lane = t & 63;
    const int wid  = t >> 6;
    const int woc  = wid >> 1; // 64-oc half
    const int wpx  = wid & 1;  // 64-pix half

    // XCD-aware chunked swizzle: 1568 blocks = 8 XCDs x 196
    const int b0 = blockIdx.x;
    const int b  = (b0 & 7) * 196 + (b0 >> 3);
    const int ptile = b >> 1;
    const int ocb   = b & 1;

    // ---- staging: wave stages rows [wid*32, +32) of A and B; 2 gl16 each ----
    // gl16 granule = 64 lanes x 16B = 16 rows x 64B. lane covers row rl=lane>>2,
    // slot lane&3. Source col pre-swizzled by row&3 so LDS stays linear.
    const int rl = lane >> 2;                    // 0..15 row in granule
    const int sc = ((lane & 3) ^ (rl & 3)) * 8;  // inverse-swizzled src col (elems)
    const unsigned short* aS[2];
    const unsigned short* bS[2];
    char* dA[2];
    char* dB[2];
#pragma unroll
    for (int c = 0; c < 2; ++c) {
        int r = wid * 32 + c * 16 + rl;
        aS[c] = wt + (size_t)(ocb * 128 + r) * CIN + sc;
        int pg  = ptile * 128 + r;
        int n   = pg / PIXIMG;
        int rem = pg - n * PIXIMG;
        int h   = rem / WW, w = rem - h * WW;
        bS[c] = xt + ((size_t)((n * HP + h) * WP + w)) * CIN + sc;
        dA[c] = lds + (wid * 32 + c * 16) * 64;
        dB[c] = lds + 8192 + (wid * 32 + c * 16) * 64;
    }

    // ---- fragment read offsets (swizzled 16B slot) ----
    const int l15 = lane & 15;
    const int lg  = lane >> 4;
    int rowA[4], rowB[4];
#pragma unroll
    for (int i = 0; i < 4; ++i) {
        int ra = woc * 64 + i * 16 + l15;
        int rb = wpx * 64 + i * 16 + l15;
        rowA[i] = ra * 64 + ((lg * 16) ^ ((ra & 3) << 4));
        rowB[i] = 8192 + rb * 64 + ((lg * 16) ^ ((rb & 3) << 4));
    }

    float4v acc[4][4];
#pragma unroll
    for (int i = 0; i < 4; ++i)
#pragma unroll
        for (int j = 0; j < 4; ++j)
            acc[i][j] = (float4v){0.f, 0.f, 0.f, 0.f};

#define STAGE(BUF, S)                                                        \
    do {                                                                     \
        const int tap_ = (S) >> 3, icq_ = (S) & 7;                           \
        const int dh_ = (tap_ * 86) >> 8, dw_ = tap_ - dh_ * 3;              \
        const size_t ao_ = (size_t)tap_ * (COUT * CIN) + icq_ * 32;          \
        const size_t bo_ = (size_t)(dh_ * WP + dw_) * CIN + icq_ * 32;       \
        gl16(aS[0] + ao_, dA[0] + (BUF));                                    \
        gl16(aS[1] + ao_, dA[1] + (BUF));                                    \
        gl16(bS[0] + bo_, dB[0] + (BUF));                                    \
        gl16(bS[1] + bo_, dB[1] + (BUF));                                    \
    } while (0)

#define COMP(BUF)                                                            \
    do {                                                                     \
        short8 af_[4], bf_[4];                                               \
        _Pragma("unroll")                                                    \
        for (int i_ = 0; i_ < 4; ++i_)                                       \
            af_[i_] = *(const short8*)(lds + (BUF) + rowA[i_]);              \
        _Pragma("unroll")                                                    \
        for (int i_ = 0; i_ < 4; ++i_)                                       \
            bf_[i_] = *(const short8*)(lds + (BUF) + rowB[i_]);              \
        _Pragma("unroll")                                                    \
        for (int oi_ = 0; oi_ < 4; ++oi_)                                    \
            _Pragma("unroll")                                                \
            for (int pi_ = 0; pi_ < 4; ++pi_)                                \
                acc[oi_][pi_] = __builtin_amdgcn_mfma_f32_16x16x32_bf16(     \
                    af_[oi_], bf_[pi_], acc[oi_][pi_], 0, 0, 0);             \
    } while (0)

    // lgkmcnt(0)-hardened barrier: LDS reads retired before crossing, so the
    // post-barrier STAGE overwrite can't race in-flight ds_reads. Global
    // (vmcnt) pipeline is NOT drained here.
#define BAR do { asm volatile("s_waitcnt lgkmcnt(0)" ::: "memory");          \
                 __builtin_amdgcn_s_barrier();                               \
                 asm volatile("" ::: "memory"); } while (0)
#define VMW4 asm volatile("s_waitcnt vmcnt(4)" ::: "memory")
#define VMW0 asm volatile("s_waitcnt vmcnt(0)" ::: "memory")

    // prologue: step 0 -> buf0 (4 loads in flight)
    STAGE(0, 0);

    // main loop: 35 double-steps (steps 0..69 computed, 1..70 staged)
#pragma unroll 1
    for (int it = 0; it < 35; ++it) {
        const int s1 = 2 * it + 1;
        STAGE(16384, s1);        // outstanding: cur 4 + next 4 = 8
        VMW4; BAR;               // cur (buf0) landed everywhere
        COMP(0);
        BAR;                     // reads retired -> buf0 free
        STAGE(0, s1 + 1);
        VMW4; BAR;               // buf1 landed
        COMP(16384);
        BAR;                     // buf1 free
    }
    // tail: steps 70 (buf0) and 71 (buf1)
    STAGE(16384, 71);
    VMW4; BAR;
    COMP(0);
    BAR;
    VMW0; BAR;                   // drain step-71 loads
    COMP(16384);
    BAR;                         // all LDS reads retired -> safe to alias
#undef STAGE
#undef COMP

    // ---- epilogue: 4 passes of [64 oc][64 pix] via LDS [64][68] f32 ----
    float* ep = (float*)lds;
#pragma unroll 1
    for (int q = 0; q < 4; ++q) {
        const int c = q >> 1;   // oc chunk
        const int p = q & 1;    // pix half
        if (woc == c && wpx == p) {
#pragma unroll
            for (int oi = 0; oi < 4; ++oi)
#pragma unroll
                for (int pi = 0; pi < 4; ++pi)
#pragma unroll
                    for (int r = 0; r < 4; ++r)
                        ep[(oi * 16 + lg * 4 + r) * 68 + (pi * 16 + l15)] =
                            acc[oi][pi][r];
        }
        __syncthreads();
        const int erow0 = t >> 4;       // 0..15
        const int ecol  = (t & 15) * 4; // 0..60
        int pg  = ptile * 128 + p * 64 + ecol;
        int n2  = pg / PIXIMG;
        int rem = pg - n2 * PIXIMG;     // 3136%4==0: float4 stays in-image
        float* ob = out + (size_t)n2 * OUTSTRIDE_N +
                    (size_t)(ocb * 128 + c * 64) * PIXIMG + rem;
#pragma unroll
        for (int rd = 0; rd < 4; ++rd) {
            int row = rd * 16 + erow0;  // 0..63
            float4v v = *(const float4v*)&ep[row * 68 + ecol];
            *(float4v*)(ob + (size_t)row * PIXIMG) = v;
        }
        __syncthreads(); // pass reads done before next pass writes
    }
}

// ---------------------------------------------------------------------------
// Fallback (ws too small): direct fp32 conv, slow but correct
// ---------------------------------------------------------------------------
__global__ __launch_bounds__(256) void k_naive(const float* __restrict__ x,
                                               const float* __restrict__ wg,
                                               const float* __restrict__ mk,
                                               float* __restrict__ out, int total) {
    int idx = blockIdx.x * 256 + threadIdx.x;
    if (idx >= total) return;
    int w  = idx % WW;
    int h  = (idx / WW) % HH;
    int oc = (idx / PIXIMG) % COUT;
    int n  = idx / (COUT * PIXIMG);
    float s = 0.f;
    for (int ic = 0; ic < CIN; ++ic) {
        const float* xp = x + (size_t)(n * CIN + ic) * PIXIMG;
        const float* wp = wg + (size_t)(oc * CIN + ic) * 9;
        const float* mp = mk + (size_t)(oc * CIN + ic) * 9;
#pragma unroll
        for (int kh = 0; kh < 3; ++kh) {
            int hy = h + kh - 1;
            if ((unsigned)hy >= HH) continue;
#pragma unroll
            for (int kw = 0; kw < 3; ++kw) {
                int wx = w + kw - 1;
                if ((unsigned)wx >= WW) continue;
                s += xp[hy * WW + wx] * wp[kh * 3 + kw] * mp[kh * 3 + kw];
            }
        }
    }
    out[idx] = s;
}

extern "C" void kernel_launch(void* const* d_in, const int* in_sizes, int n_in,
                              void* d_out, int out_size, void* d_ws, size_t ws_size,
                              hipStream_t stream) {
    const float* x  = (const float*)d_in[0];
    const float* wg = (const float*)d_in[1];
    const float* mk = (const float*)d_in[2];
    float* out = (float*)d_out;

    size_t need = XT_ELEMS * 2 + WT_ELEMS * 2 + 256;
    if (ws_size < need) {
        int total = NIMG * COUT * PIXIMG;
        k_naive<<<(total + 255) / 256, 256, 0, stream>>>(x, wg, mk, out, total);
        return;
    }

    unsigned short* xt = (unsigned short*)d_ws;
    unsigned short* wt = (unsigned short*)((char*)d_ws + XT_ELEMS * 2);

    k_transpose<<<NIMG * HP * 4, 256, 0, stream>>>(x, xt);
    k_prepw<<<(COUT * CIN) / 256, 256, 0, stream>>>(wg, mk, wt);
    k_conv<<<(TOTPIX / 128) * 2, 256, 0, stream>>>(xt, wt, out);
}

// Round 9
// 178.285 us; speedup vs baseline: 1.0032x; 1.0032x over previous
//
#include <hip/hip_runtime.h>
#include <hip/hip_bf16.h>

typedef short short8 __attribute__((ext_vector_type(8)));
typedef float float4v __attribute__((ext_vector_type(4)));

#define NIMG 32
#define CIN 256
#define COUT 256
#define HH 56
#define WW 56
#define HP 58
#define WP 58
#define PIXIMG (HH * WW)          /* 3136 */
#define TOTPIX (NIMG * PIXIMG)    /* 100352 */
#define OUTSTRIDE_N (COUT * PIXIMG)

static constexpr size_t XT_ELEMS = (size_t)NIMG * HP * WP * CIN; // bf16
static constexpr size_t WT_ELEMS = (size_t)9 * COUT * CIN;       // bf16

// fp32 -> bf16 bits, round-to-nearest-even (finite inputs only)
static __device__ __forceinline__ unsigned short f2bf(float f) {
    unsigned int u = __builtin_bit_cast(unsigned int, f);
    u = (u + 0x7fffu + ((u >> 16) & 1u)) >> 16;
    return (unsigned short)u;
}

// async global(16B/lane) -> LDS (wave-uniform base + lane*16)
static __device__ __forceinline__ void gl16(const unsigned short* g, char* l) {
    __builtin_amdgcn_global_load_lds(
        (const __attribute__((address_space(1))) void*)g,
        (__attribute__((address_space(3))) void*)l, 16, 0, 0);
}

// ---------------------------------------------------------------------------
// x (NCHW fp32) -> x_t[n][h'][w'][ic] bf16, padded; halo zeroed in-kernel.
// ---------------------------------------------------------------------------
__global__ __launch_bounds__(256) void k_transpose(const float* __restrict__ x,
                                                   unsigned short* __restrict__ xt) {
    int b   = blockIdx.x;
    int icb = b & 3;
    int hp  = (b >> 2) % HP;    // padded output row 0..57
    int n   = b / (4 * HP);
    unsigned short* rowb = xt + ((size_t)(n * HP + hp) * WP) * CIN + icb * 64;
    int t = threadIdx.x;

    if (hp == 0 || hp == HP - 1) {
        for (int idx = t; idx < WP * 8; idx += 256) {
            int wq = idx >> 3, q = idx & 7;
            *(uint4*)(rowb + (size_t)wq * CIN + q * 8) = (uint4){0, 0, 0, 0};
        }
        return;
    }
    int h = hp - 1;
    __shared__ __align__(16) char lds[64 * 128]; // [w 64][ic 64] bf16, swizzled
    int w = t & 63, icl0 = t >> 6;
    if (w < WW) {
        const float* src = x + ((size_t)(n * CIN + icb * 64 + icl0) * HH + h) * WW + w;
#pragma unroll
        for (int j = 0; j < 16; ++j) {
            float v = src[(size_t)(j * 4) * PIXIMG];
            int icl = icl0 + j * 4;
            *(unsigned short*)(lds + w * 128 + ((icl * 2) ^ ((w & 7) << 4))) = f2bf(v);
        }
    }
    __syncthreads();
    int ic4 = t & 15, wr = t >> 4;
    unsigned short* dst = rowb + (size_t)CIN + ic4 * 4; // w'=1 base
#pragma unroll
    for (int p = 0; p < 4; ++p) {
        int w2 = wr + p * 16;
        if (w2 < WW) {
            uint2 v = *(const uint2*)(lds + w2 * 128 + ((ic4 * 8) ^ ((w2 & 7) << 4)));
            *(uint2*)(dst + (size_t)w2 * CIN) = v;
        }
    }
    if (t < 32) { // zero w'=0 and w'=57 columns
        int col = (t >> 4) * (WP - 1);
        *(uint2*)(rowb + (size_t)col * CIN + (t & 15) * 4) = (uint2){0, 0};
    }
}

// ---------------------------------------------------------------------------
// wt[tap][oc][ic] = bf16(weight * mask)
// ---------------------------------------------------------------------------
__global__ __launch_bounds__(256) void k_prepw(const float* __restrict__ wgt,
                                               const float* __restrict__ msk,
                                               unsigned short* __restrict__ wt) {
    int t = blockIdx.x * 256 + threadIdx.x; // t = oc*256 + ic
    const float* wp = wgt + (size_t)t * 9;
    const float* mp = msk + (size_t)t * 9;
#pragma unroll
    for (int tap = 0; tap < 9; ++tap)
        wt[(size_t)tap * (COUT * CIN) + t] = f2bf(wp[tap] * mp[tap]);
}

// ---------------------------------------------------------------------------
// Main conv: 9 shifted GEMMs, 128x128 tile, 4 waves (2x2), BK=32,
// TRUE double-buffer in 32KB LDS with counted vmcnt (T3 minimum 2-phase),
// lgkmcnt(0)-hardened barriers (r8 race fix, kept).
// Round-9 fix vs r8: swizzle f(row) = (row&3)^((row>>2)&3) instead of
// (row&3). With 64B rows the bank-quad is g=(4*row+slot)%8; slot=lg^(row&3)
// made rows r,r+4 collide (4-way conflict, 1.49e7 counted, 1.28x slowdown).
// New f folds in row bits 2-3: enumeration gives every bank-quad exactly
// 2 lanes per 16-lane group = the same 2-way-free pattern r5 measured at 0.
// ---------------------------------------------------------------------------
__global__ __launch_bounds__(256, 4) void k_conv(const unsigned short* __restrict__ xt,
                                                 const unsigned short* __restrict__ wt,
                                                 float* __restrict__ out) {
    __shared__ __align__(16) char lds[32768];

    const int t    = threadIdx.x;
    const int lane = t & 63;
    const int wid  = t >> 6;
    const int woc  = wid >> 1; // 64-oc half
    const int wpx  = wid & 1;  // 64-pix half

    // XCD-aware chunked swizzle: 1568 blocks = 8 XCDs x 196
    const int b0 = blockIdx.x;
    const int b  = (b0 & 7) * 196 + (b0 >> 3);
    const int ptile = b >> 1;
    const int ocb   = b & 1;

    // ---- staging: wave stages rows [wid*32, +32) of A and B; 2 gl16 each ----
    // gl16 granule = 64 lanes x 16B = 16 rows x 64B; lane covers row rl=lane>>2,
    // slot lane&3. LDS row r = wid*32+c*16+rl (offsets mult. of 16), so
    // f(r) = (rl&3)^((rl>>2)&3). Source col pre-swizzled; LDS stays linear.
    const int rl = lane >> 2;                    // 0..15 row in granule
    const int fr = (rl & 3) ^ ((rl >> 2) & 3);   // swizzle for this row
    const int sc = ((lane & 3) ^ fr) * 8;        // inverse-swizzled src col (elems)
    const unsigned short* aS[2];
    const unsigned short* bS[2];
    char* dA[2];
    char* dB[2];
#pragma unroll
    for (int c = 0; c < 2; ++c) {
        int r = wid * 32 + c * 16 + rl;
        aS[c] = wt + (size_t)(ocb * 128 + r) * CIN + sc;
        int pg  = ptile * 128 + r;
        int n   = pg / PIXIMG;
        int rem = pg - n * PIXIMG;
        int h   = rem / WW, w = rem - h * WW;
        bS[c] = xt + ((size_t)((n * HP + h) * WP + w)) * CIN + sc;
        dA[c] = lds + (wid * 32 + c * 16) * 64;
        dB[c] = lds + 8192 + (wid * 32 + c * 16) * 64;
    }

    // ---- fragment read offsets (swizzled 16B slot) ----
    // Read row ra = woc*64 + i*16 + l15 => f(ra) = (l15&3)^((l15>>2)&3),
    // constant across i. Slot read = lg ^ f => returns global slot lg.
    const int l15 = lane & 15;
    const int lg  = lane >> 4;
    const int fsw = ((l15 & 3) ^ ((l15 >> 2) & 3)) << 4;
    int rowA[4], rowB[4];
#pragma unroll
    for (int i = 0; i < 4; ++i) {
        int ra = woc * 64 + i * 16 + l15;
        int rb = wpx * 64 + i * 16 + l15;
        rowA[i] = ra * 64 + ((lg * 16) ^ fsw);
        rowB[i] = 8192 + rb * 64 + ((lg * 16) ^ fsw);
    }

    float4v acc[4][4];
#pragma unroll
    for (int i = 0; i < 4; ++i)
#pragma unroll
        for (int j = 0; j < 4; ++j)
            acc[i][j] = (float4v){0.f, 0.f, 0.f, 0.f};

#define STAGE(BUF, S)                                                        \
    do {                                                                     \
        const int tap_ = (S) >> 3, icq_ = (S) & 7;                           \
        const int dh_ = (tap_ * 86) >> 8, dw_ = tap_ - dh_ * 3;              \
        const size_t ao_ = (size_t)tap_ * (COUT * CIN) + icq_ * 32;          \
        const size_t bo_ = (size_t)(dh_ * WP + dw_) * CIN + icq_ * 32;       \
        gl16(aS[0] + ao_, dA[0] + (BUF));                                    \
        gl16(aS[1] + ao_, dA[1] + (BUF));                                    \
        gl16(bS[0] + bo_, dB[0] + (BUF));                                    \
        gl16(bS[1] + bo_, dB[1] + (BUF));                                    \
    } while (0)

#define COMP(BUF)                                                            \
    do {                                                                     \
        short8 af_[4], bf_[4];                                               \
        _Pragma("unroll")                                                    \
        for (int i_ = 0; i_ < 4; ++i_)                                       \
            af_[i_] = *(const short8*)(lds + (BUF) + rowA[i_]);              \
        _Pragma("unroll")                                                    \
        for (int i_ = 0; i_ < 4; ++i_)                                       \
            bf_[i_] = *(const short8*)(lds + (BUF) + rowB[i_]);              \
        _Pragma("unroll")                                                    \
        for (int oi_ = 0; oi_ < 4; ++oi_)                                    \
            _Pragma("unroll")                                                \
            for (int pi_ = 0; pi_ < 4; ++pi_)                                \
                acc[oi_][pi_] = __builtin_amdgcn_mfma_f32_16x16x32_bf16(     \
                    af_[oi_], bf_[pi_], acc[oi_][pi_], 0, 0, 0);             \
    } while (0)

    // lgkmcnt(0)-hardened barrier: LDS reads retired before crossing, so the
    // post-barrier STAGE overwrite can't race in-flight ds_reads. Global
    // (vmcnt) pipeline is NOT drained here.
#define BAR do { asm volatile("s_waitcnt lgkmcnt(0)" ::: "memory");          \
                 __builtin_amdgcn_s_barrier();                               \
                 asm volatile("" ::: "memory"); } while (0)
#define VMW4 asm volatile("s_waitcnt vmcnt(4)" ::: "memory")
#define VMW0 asm volatile("s_waitcnt vmcnt(0)" ::: "memory")

    // prologue: step 0 -> buf0 (4 loads in flight)
    STAGE(0, 0);

    // main loop: 35 double-steps (steps 0..69 computed, 1..70 staged)
#pragma unroll 1
    for (int it = 0; it < 35; ++it) {
        const int s1 = 2 * it + 1;
        STAGE(16384, s1);        // outstanding: cur 4 + next 4 = 8
        VMW4; BAR;               // cur (buf0) landed everywhere
        COMP(0);
        BAR;                     // reads retired -> buf0 free
        STAGE(0, s1 + 1);
        VMW4; BAR;               // buf1 landed
        COMP(16384);
        BAR;                     // buf1 free
    }
    // tail: steps 70 (buf0) and 71 (buf1)
    STAGE(16384, 71);
    VMW4; BAR;
    COMP(0);
    BAR;
    VMW0; BAR;                   // drain step-71 loads
    COMP(16384);
    BAR;                         // all LDS reads retired -> safe to alias
#undef STAGE
#undef COMP

    // ---- epilogue: 4 passes of [64 oc][64 pix] via LDS [64][68] f32 ----
    float* ep = (float*)lds;
#pragma unroll 1
    for (int q = 0; q < 4; ++q) {
        const int c = q >> 1;   // oc chunk
        const int p = q & 1;    // pix half
        if (woc == c && wpx == p) {
#pragma unroll
            for (int oi = 0; oi < 4; ++oi)
#pragma unroll
                for (int pi = 0; pi < 4; ++pi)
#pragma unroll
                    for (int r = 0; r < 4; ++r)
                        ep[(oi * 16 + lg * 4 + r) * 68 + (pi * 16 + l15)] =
                            acc[oi][pi][r];
        }
        __syncthreads();
        const int erow0 = t >> 4;       // 0..15
        const int ecol  = (t & 15) * 4; // 0..60
        int pg  = ptile * 128 + p * 64 + ecol;
        int n2  = pg / PIXIMG;
        int rem = pg - n2 * PIXIMG;     // 3136%4==0: float4 stays in-image
        float* ob = out + (size_t)n2 * OUTSTRIDE_N +
                    (size_t)(ocb * 128 + c * 64) * PIXIMG + rem;
#pragma unroll
        for (int rd = 0; rd < 4; ++rd) {
            int row = rd * 16 + erow0;  // 0..63
            float4v v = *(const float4v*)&ep[row * 68 + ecol];
            *(float4v*)(ob + (size_t)row * PIXIMG) = v;
        }
        __syncthreads(); // pass reads done before next pass writes
    }
}

// ---------------------------------------------------------------------------
// Fallback (ws too small): direct fp32 conv, slow but correct
// ---------------------------------------------------------------------------
__global__ __launch_bounds__(256) void k_naive(const float* __restrict__ x,
                                               const float* __restrict__ wg,
                                               const float* __restrict__ mk,
                                               float* __restrict__ out, int total) {
    int idx = blockIdx.x * 256 + threadIdx.x;
    if (idx >= total) return;
    int w  = idx % WW;
    int h  = (idx / WW) % HH;
    int oc = (idx / PIXIMG) % COUT;
    int n  = idx / (COUT * PIXIMG);
    float s = 0.f;
    for (int ic = 0; ic < CIN; ++ic) {
        const float* xp = x + (size_t)(n * CIN + ic) * PIXIMG;
        const float* wp = wg + (size_t)(oc * CIN + ic) * 9;
        const float* mp = mk + (size_t)(oc * CIN + ic) * 9;
#pragma unroll
        for (int kh = 0; kh < 3; ++kh) {
            int hy = h + kh - 1;
            if ((unsigned)hy >= HH) continue;
#pragma unroll
            for (int kw = 0; kw < 3; ++kw) {
                int wx = w + kw - 1;
                if ((unsigned)wx >= WW) continue;
                s += xp[hy * WW + wx] * wp[kh * 3 + kw] * mp[kh * 3 + kw];
            }
        }
    }
    out[idx] = s;
}

extern "C" void kernel_launch(void* const* d_in, const int* in_sizes, int n_in,
                              void* d_out, int out_size, void* d_ws, size_t ws_size,
                              hipStream_t stream) {
    const float* x  = (const float*)d_in[0];
    const float* wg = (const float*)d_in[1];
    const float* mk = (const float*)d_in[2];
    float* out = (float*)d_out;

    size_t need = XT_ELEMS * 2 + WT_ELEMS * 2 + 256;
    if (ws_size < need) {
        int total = NIMG * COUT * PIXIMG;
        k_naive<<<(total + 255) / 256, 256, 0, stream>>>(x, wg, mk, out, total);
        return;
    }

    unsigned short* xt = (unsigned short*)d_ws;
    unsigned short* wt = (unsigned short*)((char*)d_ws + XT_ELEMS * 2);

    k_transpose<<<NIMG * HP * 4, 256, 0, stream>>>(x, xt);
    k_prepw<<<(COUT * CIN) / 256, 256, 0, stream>>>(wg, mk, wt);
    k_conv<<<(TOTPIX / 128) * 2, 256, 0, stream>>>(xt, wt, out);
}

// Round 10
// 151.218 us; speedup vs baseline: 1.1828x; 1.1790x over previous
//
#include <hip/hip_runtime.h>
#include <hip/hip_bf16.h>

typedef short short8 __attribute__((ext_vector_type(8)));
typedef float float4v __attribute__((ext_vector_type(4)));

#define NIMG 32
#define CIN 256
#define COUT 256
#define HH 56
#define WW 56
#define HP 58
#define WP 58
#define PIXIMG (HH * WW)          /* 3136 */
#define TOTPIX (NIMG * PIXIMG)    /* 100352 */
#define OUTSTRIDE_N (COUT * PIXIMG)
#define TR_BLOCKS (NIMG * HP * 4) /* 7424 transpose blocks in k_pre */

static constexpr size_t XT_ELEMS = (size_t)NIMG * HP * WP * CIN; // bf16
static constexpr size_t WT_ELEMS = (size_t)9 * COUT * CIN;       // bf16

// fp32 -> bf16 bits, round-to-nearest-even (finite inputs only)
static __device__ __forceinline__ unsigned short f2bf(float f) {
    unsigned int u = __builtin_bit_cast(unsigned int, f);
    u = (u + 0x7fffu + ((u >> 16) & 1u)) >> 16;
    return (unsigned short)u;
}

// async global(16B/lane) -> LDS (wave-uniform base + lane*16)
static __device__ __forceinline__ void gl16(const unsigned short* g, char* l) {
    __builtin_amdgcn_global_load_lds(
        (const __attribute__((address_space(1))) void*)g,
        (__attribute__((address_space(3))) void*)l, 16, 0, 0);
}

// ---------------------------------------------------------------------------
// Merged pre-pass. Blocks [0, TR_BLOCKS): x NCHW fp32 -> x_t[n][h'][w'][ic]
// bf16 (padded, halo zeroed in-kernel). Blocks [TR_BLOCKS, +256):
// wt[tap][oc][ic] = bf16(weight*mask). Merging fills the transpose tail with
// prepw work and saves one launch gap.
// ---------------------------------------------------------------------------
__global__ __launch_bounds__(256) void k_pre(const float* __restrict__ x,
                                             const float* __restrict__ wgt,
                                             const float* __restrict__ msk,
                                             unsigned short* __restrict__ xt,
                                             unsigned short* __restrict__ wt) {
    int t = threadIdx.x;
    if (blockIdx.x >= TR_BLOCKS) {
        // ---- prepw part ----
        int g = (blockIdx.x - TR_BLOCKS) * 256 + t; // g = oc*256 + ic
        const float* wp = wgt + (size_t)g * 9;
        const float* mp = msk + (size_t)g * 9;
#pragma unroll
        for (int tap = 0; tap < 9; ++tap)
            wt[(size_t)tap * (COUT * CIN) + g] = f2bf(wp[tap] * mp[tap]);
        return;
    }
    // ---- transpose part ----
    int b   = blockIdx.x;
    int icb = b & 3;
    int hp  = (b >> 2) % HP;    // padded output row 0..57
    int n   = b / (4 * HP);
    unsigned short* rowb = xt + ((size_t)(n * HP + hp) * WP) * CIN + icb * 64;

    if (hp == 0 || hp == HP - 1) {
        for (int idx = t; idx < WP * 8; idx += 256) {
            int wq = idx >> 3, q = idx & 7;
            *(uint4*)(rowb + (size_t)wq * CIN + q * 8) = (uint4){0, 0, 0, 0};
        }
        return;
    }
    int h = hp - 1;
    __shared__ __align__(16) char lds[64 * 128]; // [w 64][ic 64] bf16, swizzled
    int w = t & 63, icl0 = t >> 6;
    if (w < WW) {
        const float* src = x + ((size_t)(n * CIN + icb * 64 + icl0) * HH + h) * WW + w;
#pragma unroll
        for (int j = 0; j < 16; ++j) {
            float v = src[(size_t)(j * 4) * PIXIMG];
            int icl = icl0 + j * 4;
            *(unsigned short*)(lds + w * 128 + ((icl * 2) ^ ((w & 7) << 4))) = f2bf(v);
        }
    }
    __syncthreads();
    int ic4 = t & 15, wr = t >> 4;
    unsigned short* dst = rowb + (size_t)CIN + ic4 * 4; // w'=1 base
#pragma unroll
    for (int p = 0; p < 4; ++p) {
        int w2 = wr + p * 16;
        if (w2 < WW) {
            uint2 v = *(const uint2*)(lds + w2 * 128 + ((ic4 * 8) ^ ((w2 & 7) << 4)));
            *(uint2*)(dst + (size_t)w2 * CIN) = v;
        }
    }
    if (t < 32) { // zero w'=0 and w'=57 columns
        int col = (t >> 4) * (WP - 1);
        *(uint2*)(rowb + (size_t)col * CIN + (t & 15) * 4) = (uint2){0, 0};
    }
}

// ---------------------------------------------------------------------------
// Main conv (r5/r6 champion, verbatim): 9 shifted GEMMs, m97 structure:
// 128x128 tile, 4 waves (2x2), BK=64, SINGLE 32KB A+B buffer,
// {STAGE; sync; COMPUTE; sync} per K-step. LDS 33792B; 12 waves/CU;
// cross-block wave overlap absorbs the per-step vmcnt(0) drains (m114).
// Measured: 123 us, MfmaUtil 43, bank conflicts 0. Overlapped-staging
// variants (dbuf/8-phase/counted-vmcnt; r2,r3/4,r8/9) all regressed —
// write/read LDS contention + per-step overhead eat the pipeline gain.
// ---------------------------------------------------------------------------
__global__ __launch_bounds__(256, 4) void k_conv(const unsigned short* __restrict__ xt,
                                                 const unsigned short* __restrict__ wt,
                                                 float* __restrict__ out) {
    __shared__ __align__(16) char lds[64 * 132 * 4]; // 33792 B
    // K-loop uses first 32KB: A [128 oc][64 ic] @0, B [128 pix][64 ic] @16384

    const int t    = threadIdx.x;
    const int lane = t & 63;
    const int wid  = t >> 6;
    const int woc  = wid >> 1; // 64-oc half
    const int wpx  = wid & 1;  // 64-pix half

    // XCD-aware chunked swizzle: 1568 blocks = 8 XCDs x 196
    const int b0 = blockIdx.x;
    const int b  = (b0 & 7) * 196 + (b0 >> 3);
    const int ptile = b >> 1;
    const int ocb   = b & 1;

    // ---- staging: wave stages rows [wid*32, +32) of A and B; 4 gl16 each ----
    const int rl  = lane >> 3;                 // row-within-8 at dest
    const int sc  = ((lane & 7) ^ rl) * 8;     // inverse-swizzled src col (elems)
    const unsigned short* aS[4];
    const unsigned short* bS[4];
    char* dA[4];
    char* dB[4];
#pragma unroll
    for (int c = 0; c < 4; ++c) {
        int r = wid * 32 + c * 8 + rl;
        aS[c] = wt + (size_t)(ocb * 128 + r) * CIN + sc;
        int pg  = ptile * 128 + r;
        int n   = pg / PIXIMG;
        int rem = pg - n * PIXIMG;
        int h   = rem / WW, w = rem - h * WW;
        bS[c] = xt + ((size_t)((n * HP + h) * WP + w)) * CIN + sc;
        dA[c] = lds + (wid * 32 + c * 8) * 128;
        dB[c] = lds + 16384 + (wid * 32 + c * 8) * 128;
    }

    // ---- fragment read offsets ----
    const int l15  = lane & 15;
    const int lg   = lane >> 4;
    const int swzf = (lane & 7) << 4;
    int colk[2];
    colk[0] = (lg * 16) ^ swzf;
    colk[1] = (64 + lg * 16) ^ swzf;
    int rowA[4], rowB[4];
#pragma unroll
    for (int i = 0; i < 4; ++i) {
        rowA[i] = (woc * 64 + i * 16 + l15) * 128;
        rowB[i] = 16384 + (wpx * 64 + i * 16 + l15) * 128;
    }

    float4v acc[4][4];
#pragma unroll
    for (int i = 0; i < 4; ++i)
#pragma unroll
        for (int j = 0; j < 4; ++j)
            acc[i][j] = (float4v){0.f, 0.f, 0.f, 0.f};

    // ---- main loop: 36 K-steps, single-buffered (m97 structure) ----
#pragma unroll 1
    for (int s = 0; s < 36; ++s) {
        const int tap = s >> 2;
        const int dh  = (tap * 86) >> 8;
        const int dw  = tap - dh * 3;
        const size_t ao = (size_t)tap * (COUT * CIN) + (size_t)((s & 3) << 6);
        const size_t bo = (size_t)(dh * WP + dw) * CIN + (size_t)((s & 3) << 6);
#pragma unroll
        for (int c = 0; c < 4; ++c) gl16(aS[c] + ao, dA[c]);
#pragma unroll
        for (int c = 0; c < 4; ++c) gl16(bS[c] + bo, dB[c]);
        __syncthreads(); // vmcnt(0) drain + barrier: buffer ready
#pragma unroll
        for (int kk = 0; kk < 2; ++kk) {
            short8 af[4], bfr[4];
#pragma unroll
            for (int i = 0; i < 4; ++i)
                af[i] = *(const short8*)(lds + rowA[i] + colk[kk]);
#pragma unroll
            for (int i = 0; i < 4; ++i)
                bfr[i] = *(const short8*)(lds + rowB[i] + colk[kk]);
#pragma unroll
            for (int oi = 0; oi < 4; ++oi)
#pragma unroll
                for (int pi = 0; pi < 4; ++pi)
                    acc[oi][pi] = __builtin_amdgcn_mfma_f32_16x16x32_bf16(
                        af[oi], bfr[pi], acc[oi][pi], 0, 0, 0);
        }
        __syncthreads(); // reads done before next stage overwrites
    }

    // ---- epilogue: 2 chunks of 64 oc via LDS transpose, coalesced stores ----
    float* ep = (float*)lds; // [64 oc][132] f32, pad kills write conflicts
#pragma unroll 1
    for (int c = 0; c < 2; ++c) {
        if (woc == c) {
#pragma unroll
            for (int oi = 0; oi < 4; ++oi)
#pragma unroll
                for (int pi = 0; pi < 4; ++pi)
#pragma unroll
                    for (int r = 0; r < 4; ++r)
                        ep[(oi * 16 + lg * 4 + r) * 132 +
                           (wpx * 64 + pi * 16 + l15)] = acc[oi][pi][r];
        }
        __syncthreads();
        const int rrow = t >> 5;        // 0..7
        const int rcol = (t & 31) * 4;  // 0..124
        int pg  = ptile * 128 + rcol;
        int n2  = pg / PIXIMG;
        int rem = pg - n2 * PIXIMG;     // 3136%4==0: float4 stays in-image
        float* ob = out + (size_t)n2 * OUTSTRIDE_N +
                    (size_t)(ocb * 128 + c * 64) * PIXIMG + rem;
#pragma unroll
        for (int rd = 0; rd < 8; ++rd) {
            int row = rd * 8 + rrow;    // 0..63
            float4v v = *(const float4v*)&ep[row * 132 + rcol];
            *(float4v*)(ob + (size_t)row * PIXIMG) = v;
        }
        __syncthreads(); // chunk reads done before next chunk's writes
    }
}

// ---------------------------------------------------------------------------
// Fallback (ws too small): direct fp32 conv, slow but correct
// ---------------------------------------------------------------------------
__global__ __launch_bounds__(256) void k_naive(const float* __restrict__ x,
                                               const float* __restrict__ wg,
                                               const float* __restrict__ mk,
                                               float* __restrict__ out, int total) {
    int idx = blockIdx.x * 256 + threadIdx.x;
    if (idx >= total) return;
    int w  = idx % WW;
    int h  = (idx / WW) % HH;
    int oc = (idx / PIXIMG) % COUT;
    int n  = idx / (COUT * PIXIMG);
    float s = 0.f;
    for (int ic = 0; ic < CIN; ++ic) {
        const float* xp = x + (size_t)(n * CIN + ic) * PIXIMG;
        const float* wp = wg + (size_t)(oc * CIN + ic) * 9;
        const float* mp = mk + (size_t)(oc * CIN + ic) * 9;
#pragma unroll
        for (int kh = 0; kh < 3; ++kh) {
            int hy = h + kh - 1;
            if ((unsigned)hy >= HH) continue;
#pragma unroll
            for (int kw = 0; kw < 3; ++kw) {
                int wx = w + kw - 1;
                if ((unsigned)wx >= WW) continue;
                s += xp[hy * WW + wx] * wp[kh * 3 + kw] * mp[kh * 3 + kw];
            }
        }
    }
    out[idx] = s;
}

extern "C" void kernel_launch(void* const* d_in, const int* in_sizes, int n_in,
                              void* d_out, int out_size, void* d_ws, size_t ws_size,
                              hipStream_t stream) {
    const float* x  = (const float*)d_in[0];
    const float* wg = (const float*)d_in[1];
    const float* mk = (const float*)d_in[2];
    float* out = (float*)d_out;

    size_t need = XT_ELEMS * 2 + WT_ELEMS * 2 + 256;
    if (ws_size < need) {
        int total = NIMG * COUT * PIXIMG;
        k_naive<<<(total + 255) / 256, 256, 0, stream>>>(x, wg, mk, out, total);
        return;
    }

    unsigned short* xt = (unsigned short*)d_ws;
    unsigned short* wt = (unsigned short*)((char*)d_ws + XT_ELEMS * 2);

    k_pre<<<TR_BLOCKS + (COUT * CIN) / 256, 256, 0, stream>>>(x, wg, mk, xt, wt);
    k_conv<<<(TOTPIX / 128) * 2, 256, 0, stream>>>(xt, wt, out);
}